// Round 2
// 272.486 us; speedup vs baseline: 1.0843x; 1.0843x over previous
//
#include <hip/hip_runtime.h>
#include <math.h>

#define BATCHES 8192
#define D_IN    400
#define D_OUT   100
#define QD      10
#define KT      64
#define NKT     7                              // 7*64 = 448 >= 400
#define MTILES  7                              // 7*16 = 112 >= 100
#define WFSZ    (NKT * MTILES * 2 * 64 * 8)    // 50176 shorts per plane
#define XB      648                            // floats per batch region (640 + 8 pad)
#define NW      4                              // waves per block

using bf16x8 = __attribute__((ext_vector_type(8))) short;
using f32x4  = __attribute__((ext_vector_type(4))) float;

// ---- wave-64 sum via DPP (row_shr + row_bcast), result broadcast via SGPR ----
// Chain: 6 VALU-latency DPP adds + 1 v_readlane, ~60 cyc — replaces the
// 6-level ds_swizzle/ds_bpermute butterfly (~700 cyc) that dominated the wall.
template <int CTRL>
__device__ __forceinline__ float dpp_add(float x) {
  int s = __builtin_amdgcn_update_dpp(0, __builtin_bit_cast(int, x),
                                      CTRL, 0xF, 0xF, true);
  return x + __builtin_bit_cast(float, s);
}

__device__ __forceinline__ float wsum64(float x) {
  x = dpp_add<0x111>(x);   // row_shr:1
  x = dpp_add<0x112>(x);   // row_shr:2
  x = dpp_add<0x114>(x);   // row_shr:4
  x = dpp_add<0x118>(x);   // row_shr:8  -> lane15 of each row has row sum
  x = dpp_add<0x142>(x);   // row_bcast:15 -> lane31 has rows0+1, lane63 rows2+3
  x = dpp_add<0x143>(x);   // row_bcast:31 -> lane63 has total
  return __builtin_bit_cast(float,
      __builtin_amdgcn_readlane(__builtin_bit_cast(int, x), 63));
}

__device__ __forceinline__ float lane_bcast(float x, int lane) {
  return __builtin_bit_cast(float,
      __builtin_amdgcn_readlane(__builtin_bit_cast(int, x), lane));
}

// ---------- prep: W (100,400) fp32 -> A-fragment-ordered bf16 hi/lo planes ----
// layout: e = (((kt*7+mt)*2+ks)*64 + lane)*8 + j ; lane = quad*16 + row16
// padded entries (o>=100 or k>=400) written as ZERO (k-pad must be finite).
__global__ __launch_bounds__(256) void wprep_kernel(const float* __restrict__ W,
                                                    short* __restrict__ wfh,
                                                    short* __restrict__ wfl) {
  const int e = blockIdx.x * 256 + threadIdx.x;
  if (e >= WFSZ) return;
  const int j = e & 7, lane = (e >> 3) & 63, ks = (e >> 9) & 1, mtkt = e >> 10;
  const int kt = mtkt / MTILES, mt = mtkt - kt * MTILES;
  const int o = mt * 16 + (lane & 15);
  const int k = kt * KT + ks * 32 + (lane >> 4) * 8 + j;
  const float w = (o < D_OUT && k < D_IN) ? W[o * D_IN + k] : 0.f;
  __bf16 h = (__bf16)w;
  float hf = (float)h;
  __bf16 l = (__bf16)(w - hf);
  wfh[e] = __builtin_bit_cast(short, h);
  wfl[e] = __builtin_bit_cast(short, l);
}

// ---------- fused: Y = W@X[b] (MFMA, bf16 3-split) then Householder QR -------

// Round-1-proven QR (LAPACK sgeqrf convention) + staging glue. stg holds the
// 100x10 panel (row-major); dst is out + b*1000. All wave-private, no barriers.
__device__ __forceinline__ void qr_and_store(const f32x4* acc, float* stg,
                                             float* dst, int lane, int col,
                                             int quad) {
  // C-layout (col=lane&15, row=quad*4+rr) -> row-major panel in LDS
  if (col < QD) {
    #pragma unroll
    for (int mt = 0; mt < MTILES; ++mt)
      #pragma unroll
      for (int rr = 0; rr < 4; ++rr) {
        const int o = mt * 16 + quad * 4 + rr;
        if (o < D_OUT) stg[o * QD + col] = acc[mt][rr];
      }
  }
  // lane r owns rows r and r+64 of the zero-padded 128-row panel
  const int r = lane;
  float a0[QD], a1[QD];
  #pragma unroll
  for (int q = 0; q < QD; ++q) a0[q] = stg[r * QD + q];
  const bool has1 = (r + 64) < D_OUT;
  #pragma unroll
  for (int q = 0; q < QD; ++q) a1[q] = has1 ? stg[(r + 64) * QD + q] : 0.f;

  float v0[QD], v1[QD], tau[QD];
  #pragma unroll
  for (int j = 0; j < QD; ++j) {
    float cj0  = (r >= j) ? a0[j] : 0.f;
    float part = cj0 * cj0 + a1[j] * a1[j];
    float sig  = wsum64(part);
    float alpha = lane_bcast(a0[j], j);
    float nrm  = sqrtf(sig);
    float beta = (alpha >= 0.f) ? -nrm : nrm;
    float tj   = (nrm > 0.f) ? (beta - alpha) / beta : 0.f;
    float inv  = (nrm > 0.f) ? 1.f / (alpha - beta) : 0.f;
    tau[j] = tj;
    v0[j]  = (r == j) ? 1.f : ((r > j) ? a0[j] * inv : 0.f);
    v1[j]  = a1[j] * inv;
    #pragma unroll
    for (int k = j + 1; k < QD; ++k) {
      float p = v0[j] * a0[k] + v1[j] * a1[k];
      float s = wsum64(p) * tj;
      a0[k] -= s * v0[j];
      a1[k] -= s * v1[j];
    }
  }
  float q0[QD], q1[QD];
  #pragma unroll
  for (int c = 0; c < QD; ++c) { q0[c] = (r == c) ? 1.f : 0.f; q1[c] = 0.f; }
  #pragma unroll
  for (int j = QD - 1; j >= 0; --j) {
    #pragma unroll
    for (int c = j; c < QD; ++c) {
      float p = v0[j] * q0[c] + v1[j] * q1[c];
      float s = wsum64(p) * tau[j];
      q0[c] -= s * v0[j];
      q1[c] -= s * v1[j];
    }
  }
  // Q back to LDS, then coalesced float4 store
  #pragma unroll
  for (int c = 0; c < QD; ++c) stg[r * QD + c] = q0[c];
  if (has1) {
    #pragma unroll
    for (int c = 0; c < QD; ++c) stg[(r + 64) * QD + c] = q1[c];
  }
  const float4* src = (const float4*)stg;
  float4* d4 = (float4*)dst;
  #pragma unroll
  for (int u = r; u < (D_OUT * QD) / 4; u += 64) d4[u] = src[u];
}

__global__ __launch_bounds__(256, 3) void fused_kernel(const float* __restrict__ X,
                                                       const short* __restrict__ wfh,
                                                       const short* __restrict__ wfl,
                                                       float* __restrict__ out) {
  __shared__ float xstg[NW * 2 * XB];   // wave-private fp32 X tiles / QR staging
  const int tid  = threadIdx.x;
  const int lane = tid & 63;
  const int wv   = __builtin_amdgcn_readfirstlane(tid >> 6);
  const long b0  = (long)blockIdx.x * (NW * 2) + wv * 2;
  float* xs = xstg + wv * (2 * XB);
  const int col = lane & 15, quad = lane >> 4;

  f32x4 acc0[MTILES], acc1[MTILES];
  #pragma unroll
  for (int t = 0; t < MTILES; ++t) {
    acc0[t] = (f32x4){0.f, 0.f, 0.f, 0.f};
    acc1[t] = (f32x4){0.f, 0.f, 0.f, 0.f};
  }

  // register prefetch of tile 0 (all 640 floats/batch valid at kt=0)
  float4 pre[5];
  #pragma unroll
  for (int u = 0; u < 5; ++u) {
    const int idx = lane + u * 64;          // 0..319 over [b0 tile | b1 tile]
    const int bsel = idx >= 160 ? 1 : 0;
    const int within = idx - bsel * 160;    // float4 index in tile
    pre[u] = *(const float4*)(X + (b0 + bsel) * (long)(D_IN * QD) + within * 4);
  }

  #pragma unroll 1
  for (int kt = 0; kt < NKT; ++kt) {
    const int k0 = kt * KT;
    // ---- commit prefetched tile to this wave's LDS region ----
    #pragma unroll
    for (int u = 0; u < 5; ++u) {
      const int idx = lane + u * 64;
      const int bsel = idx >= 160 ? 1 : 0;
      const int within = idx - bsel * 160;
      *(float4*)&xs[bsel * XB + within * 4] = pre[u];
    }
    // ---- register-prefetch next tile (zero-fill past k=400) ----
    if (kt + 1 < NKT) {
      const int nk0 = k0 + KT;
      const int vf4 = (nk0 + KT <= D_IN) ? 160 : ((D_IN - nk0) * QD) / 4;  // 160 | 40
      #pragma unroll
      for (int u = 0; u < 5; ++u) {
        const int idx = lane + u * 64;
        const int bsel = idx >= 160 ? 1 : 0;
        const int within = idx - bsel * 160;
        float4 v = {0.f, 0.f, 0.f, 0.f};
        if (within < vf4)
          v = *(const float4*)(X + (b0 + bsel) * (long)(D_IN * QD) + nk0 * QD + within * 4);
        pre[u] = v;
      }
    }
    // ---- MFMA over this tile; A-frags straight from global (L1/L2-resident) --
    const short* wh_kt = wfh + (long)kt * (MTILES * 2 * 64 * 8);
    const short* wl_kt = wfl + (long)kt * (MTILES * 2 * 64 * 8);
    #pragma unroll
    for (int ks = 0; ks < 2; ++ks) {
      // B-frag gather from fp32 LDS (2-way banks = free) + in-register split.
      // cols 10..15 read neighboring rows -> garbage only in unread acc cols.
      bf16x8 b0h, b0l, b1h, b1l;
      #pragma unroll
      for (int m = 0; m < 8; ++m) {
        const int fo = (ks * 32 + quad * 8 + m) * QD + col;
        float x0 = xs[fo];
        float x1 = xs[XB + fo];
        __bf16 h0 = (__bf16)x0; float f0 = (float)h0; __bf16 g0 = (__bf16)(x0 - f0);
        __bf16 h1 = (__bf16)x1; float f1 = (float)h1; __bf16 g1 = (__bf16)(x1 - f1);
        b0h[m] = __builtin_bit_cast(short, h0); b0l[m] = __builtin_bit_cast(short, g0);
        b1h[m] = __builtin_bit_cast(short, h1); b1l[m] = __builtin_bit_cast(short, g1);
      }
      #pragma unroll
      for (int mt = 0; mt < MTILES; ++mt) {
        const int ao = ((mt * 2 + ks) * 64 + lane) * 8;
        bf16x8 ah = *(const bf16x8*)(wh_kt + ao);
        bf16x8 al = *(const bf16x8*)(wl_kt + ao);
        acc0[mt] = __builtin_amdgcn_mfma_f32_16x16x32_bf16(ah, b0h, acc0[mt], 0, 0, 0);
        acc0[mt] = __builtin_amdgcn_mfma_f32_16x16x32_bf16(al, b0h, acc0[mt], 0, 0, 0);
        acc0[mt] = __builtin_amdgcn_mfma_f32_16x16x32_bf16(ah, b0l, acc0[mt], 0, 0, 0);
        acc1[mt] = __builtin_amdgcn_mfma_f32_16x16x32_bf16(ah, b1h, acc1[mt], 0, 0, 0);
        acc1[mt] = __builtin_amdgcn_mfma_f32_16x16x32_bf16(al, b1h, acc1[mt], 0, 0, 0);
        acc1[mt] = __builtin_amdgcn_mfma_f32_16x16x32_bf16(ah, b1l, acc1[mt], 0, 0, 0);
      }
    }
  }

  // ---- fused QR + store, one batch at a time (stg reuses the X region) ----
  qr_and_store(acc0, xs, out + b0 * (long)(D_OUT * QD), lane, col, quad);
  qr_and_store(acc1, xs, out + (b0 + 1) * (long)(D_OUT * QD), lane, col, quad);
}

extern "C" void kernel_launch(void* const* d_in, const int* in_sizes, int n_in,
                              void* d_out, int out_size, void* d_ws, size_t ws_size,
                              hipStream_t stream) {
  const float* X = (const float*)d_in[0];   // (8192, 400, 10) fp32
  const float* W = (const float*)d_in[1];   // (100, 400) fp32
  float* out = (float*)d_out;               // (8192, 100, 10) fp32
  short* wfh = (short*)d_ws;                // 50176 shorts
  short* wfl = wfh + WFSZ;                  // 50176 shorts (offset 100352 B, 16-aligned)
  hipLaunchKernelGGL(wprep_kernel, dim3((WFSZ + 255) / 256), dim3(256), 0, stream,
                     W, wfh, wfl);
  hipLaunchKernelGGL(fused_kernel, dim3(BATCHES / (NW * 2)), dim3(256), 0, stream,
                     X, wfh, wfl, out);
}

// Round 3
// 260.644 us; speedup vs baseline: 1.1336x; 1.0454x over previous
//
#include <hip/hip_runtime.h>
#include <math.h>

#define BATCHES 8192
#define D_IN    400
#define D_OUT   100
#define QD      10
#define KT      64
#define NKT     7                              // 7*64 = 448 >= 400
#define MTILES  7                              // 7*16 = 112 >= 100
#define WFSZ    (NKT * MTILES * 2 * 64 * 8)    // 50176 shorts per plane
#define XR      1008                           // floats per wave region (>=1000 for QR stg, >=648 for X tile)
#define NW      4                              // waves per block, 1 batch per wave

using bf16x8 = __attribute__((ext_vector_type(8))) short;
using f32x4  = __attribute__((ext_vector_type(4))) float;

// ---- wave-64 sum via DPP (row_shr + row_bcast), result broadcast via SGPR ----
template <int CTRL>
__device__ __forceinline__ float dpp_add(float x) {
  int s = __builtin_amdgcn_update_dpp(0, __builtin_bit_cast(int, x),
                                      CTRL, 0xF, 0xF, true);
  return x + __builtin_bit_cast(float, s);
}

__device__ __forceinline__ float wsum64(float x) {
  x = dpp_add<0x111>(x);   // row_shr:1
  x = dpp_add<0x112>(x);   // row_shr:2
  x = dpp_add<0x114>(x);   // row_shr:4
  x = dpp_add<0x118>(x);   // row_shr:8  -> lane15 of each row has row sum
  x = dpp_add<0x142>(x);   // row_bcast:15
  x = dpp_add<0x143>(x);   // row_bcast:31 -> lane63 has total
  return __builtin_bit_cast(float,
      __builtin_amdgcn_readlane(__builtin_bit_cast(int, x), 63));
}

__device__ __forceinline__ float lane_bcast(float x, int lane) {
  return __builtin_bit_cast(float,
      __builtin_amdgcn_readlane(__builtin_bit_cast(int, x), lane));
}

// ---------- prep: W (100,400) fp32 -> A-fragment-ordered bf16 hi/lo planes ----
// layout: e = (((kt*7+mt)*2+ks)*64 + lane)*8 + j ; lane = quad*16 + row16
// padded entries (o>=100 or k>=400) written as ZERO (k-pad must be finite).
__global__ __launch_bounds__(256) void wprep_kernel(const float* __restrict__ W,
                                                    short* __restrict__ wfh,
                                                    short* __restrict__ wfl) {
  const int e = blockIdx.x * 256 + threadIdx.x;
  if (e >= WFSZ) return;
  const int j = e & 7, lane = (e >> 3) & 63, ks = (e >> 9) & 1, mtkt = e >> 10;
  const int kt = mtkt / MTILES, mt = mtkt - kt * MTILES;
  const int o = mt * 16 + (lane & 15);
  const int k = kt * KT + ks * 32 + (lane >> 4) * 8 + j;
  const float w = (o < D_OUT && k < D_IN) ? W[o * D_IN + k] : 0.f;
  __bf16 h = (__bf16)w;
  float hf = (float)h;
  __bf16 l = (__bf16)(w - hf);
  wfh[e] = __builtin_bit_cast(short, h);
  wfl[e] = __builtin_bit_cast(short, l);
}

// ---------- fused: Y = W@X[b] (MFMA, bf16 3-split) then Householder QR -------

// LAPACK sgeqrf convention. stg holds the 100x10 panel (row-major); dst is
// out + b*1000. All wave-private, no barriers. Divides replaced with
// v_rcp_f32 via tau = 1+|a|/nrm, 1/(a-beta) = sign(a)/(|a|+nrm).
__device__ __forceinline__ void qr_and_store(const f32x4* acc, float* stg,
                                             float* dst, int lane, int col,
                                             int quad) {
  // C-layout (col=lane&15, row=quad*4+rr) -> row-major panel in LDS
  if (col < QD) {
    #pragma unroll
    for (int mt = 0; mt < MTILES; ++mt)
      #pragma unroll
      for (int rr = 0; rr < 4; ++rr) {
        const int o = mt * 16 + quad * 4 + rr;
        if (o < D_OUT) stg[o * QD + col] = acc[mt][rr];
      }
  }
  // lane r owns rows r and r+64 of the zero-padded 128-row panel
  const int r = lane;
  float a0[QD], a1[QD];
  #pragma unroll
  for (int q = 0; q < QD; ++q) a0[q] = stg[r * QD + q];
  const bool has1 = (r + 64) < D_OUT;
  #pragma unroll
  for (int q = 0; q < QD; ++q) a1[q] = has1 ? stg[(r + 64) * QD + q] : 0.f;

  float v0[QD], v1[QD], tau[QD];
  #pragma unroll
  for (int j = 0; j < QD; ++j) {
    float cj0  = (r >= j) ? a0[j] : 0.f;
    float part = cj0 * cj0 + a1[j] * a1[j];
    float sig  = wsum64(part);
    float alpha = lane_bcast(a0[j], j);
    float nrm  = __builtin_amdgcn_sqrtf(sig);
    float aab  = fabsf(alpha);
    float rn   = __builtin_amdgcn_rcpf(nrm);
    float rd   = __builtin_amdgcn_rcpf(aab + nrm);
    float sgn  = (alpha >= 0.f) ? 1.f : -1.f;
    float tj   = (sig > 0.f) ? (1.f + aab * rn) : 0.f;
    float inv  = (sig > 0.f) ? sgn * rd : 0.f;      // 1/(alpha - beta)
    tau[j] = tj;
    v0[j]  = (r == j) ? 1.f : ((r > j) ? a0[j] * inv : 0.f);
    v1[j]  = a1[j] * inv;
    #pragma unroll
    for (int k = j + 1; k < QD; ++k) {
      float p = v0[j] * a0[k] + v1[j] * a1[k];
      float s = wsum64(p) * tj;
      a0[k] -= s * v0[j];
      a1[k] -= s * v1[j];
    }
  }
  float q0[QD], q1[QD];
  #pragma unroll
  for (int c = 0; c < QD; ++c) { q0[c] = (r == c) ? 1.f : 0.f; q1[c] = 0.f; }
  #pragma unroll
  for (int j = QD - 1; j >= 0; --j) {
    #pragma unroll
    for (int c = j; c < QD; ++c) {
      float p = v0[j] * q0[c] + v1[j] * q1[c];
      float s = wsum64(p) * tau[j];
      q0[c] -= s * v0[j];
      q1[c] -= s * v1[j];
    }
  }
  // Q back to LDS, then coalesced float4 store
  #pragma unroll
  for (int c = 0; c < QD; ++c) stg[r * QD + c] = q0[c];
  if (has1) {
    #pragma unroll
    for (int c = 0; c < QD; ++c) stg[(r + 64) * QD + c] = q1[c];
  }
  const float4* src = (const float4*)stg;
  float4* d4 = (float4*)dst;
  #pragma unroll
  for (int u = r; u < (D_OUT * QD) / 4; u += 64) d4[u] = src[u];
}

__global__ __launch_bounds__(256, 4) void fused_kernel(const float* __restrict__ X,
                                                       const short* __restrict__ wfh,
                                                       const short* __restrict__ wfl,
                                                       float* __restrict__ out) {
  __shared__ float xstg[NW * XR];       // wave-private fp32 X tile / QR staging
  const int tid  = threadIdx.x;
  const int lane = tid & 63;
  const int wv   = __builtin_amdgcn_readfirstlane(tid >> 6);
  const long b   = (long)blockIdx.x * NW + wv;   // one batch per wave
  float* xs = xstg + wv * XR;
  const int col = lane & 15, quad = lane >> 4;

  f32x4 acc[MTILES];
  #pragma unroll
  for (int t = 0; t < MTILES; ++t) acc[t] = (f32x4){0.f, 0.f, 0.f, 0.f};

  // register prefetch of tile 0 (160 float4; all valid at kt=0)
  float4 pre[3];
  #pragma unroll
  for (int u = 0; u < 3; ++u) {
    const int idx = lane + u * 64;
    pre[u] = (float4){0.f, 0.f, 0.f, 0.f};
    if (idx < 160)
      pre[u] = *(const float4*)(X + b * (long)(D_IN * QD) + idx * 4);
  }

  #pragma unroll 1
  for (int kt = 0; kt < NKT; ++kt) {
    const int k0 = kt * KT;
    // ---- commit prefetched tile to this wave's LDS region ----
    #pragma unroll
    for (int u = 0; u < 3; ++u) {
      const int idx = lane + u * 64;
      if (idx < 160) *(float4*)&xs[idx * 4] = pre[u];
    }
    // ---- register-prefetch next tile (zero-fill past k=400) ----
    if (kt + 1 < NKT) {
      const int nk0 = k0 + KT;
      const int vf4 = (nk0 + KT <= D_IN) ? 160 : ((D_IN - nk0) * QD) / 4;  // 160 | 40
      #pragma unroll
      for (int u = 0; u < 3; ++u) {
        const int idx = lane + u * 64;
        float4 v = {0.f, 0.f, 0.f, 0.f};
        if (idx < vf4)
          v = *(const float4*)(X + b * (long)(D_IN * QD) + nk0 * QD + idx * 4);
        pre[u] = v;
      }
    }
    // ---- MFMA over this tile; A-frags straight from global (L1/L2-resident) --
    const short* wh_kt = wfh + (long)kt * (MTILES * 2 * 64 * 8);
    const short* wl_kt = wfl + (long)kt * (MTILES * 2 * 64 * 8);
    #pragma unroll
    for (int ks = 0; ks < 2; ++ks) {
      // B-frag gather from fp32 LDS (2-way banks = free) + in-register split.
      // cols 10..15 read pad/neighbor rows -> garbage only in unread acc cols.
      bf16x8 bh, bl;
      #pragma unroll
      for (int m = 0; m < 8; ++m) {
        const int fo = (ks * 32 + quad * 8 + m) * QD + col;
        float x0 = xs[fo];
        __bf16 h0 = (__bf16)x0; float f0 = (float)h0; __bf16 g0 = (__bf16)(x0 - f0);
        bh[m] = __builtin_bit_cast(short, h0);
        bl[m] = __builtin_bit_cast(short, g0);
      }
      #pragma unroll
      for (int mt = 0; mt < MTILES; ++mt) {
        const int ao = ((mt * 2 + ks) * 64 + lane) * 8;
        bf16x8 ah = *(const bf16x8*)(wh_kt + ao);
        bf16x8 al = *(const bf16x8*)(wl_kt + ao);
        acc[mt] = __builtin_amdgcn_mfma_f32_16x16x32_bf16(ah, bh, acc[mt], 0, 0, 0);
        acc[mt] = __builtin_amdgcn_mfma_f32_16x16x32_bf16(al, bh, acc[mt], 0, 0, 0);
        acc[mt] = __builtin_amdgcn_mfma_f32_16x16x32_bf16(ah, bl, acc[mt], 0, 0, 0);
      }
    }
  }

  // ---- fused QR + store (stg reuses the X region) ----
  qr_and_store(acc, xs, out + b * (long)(D_OUT * QD), lane, col, quad);
}

extern "C" void kernel_launch(void* const* d_in, const int* in_sizes, int n_in,
                              void* d_out, int out_size, void* d_ws, size_t ws_size,
                              hipStream_t stream) {
  const float* X = (const float*)d_in[0];   // (8192, 400, 10) fp32
  const float* W = (const float*)d_in[1];   // (100, 400) fp32
  float* out = (float*)d_out;               // (8192, 100, 10) fp32
  short* wfh = (short*)d_ws;                // 50176 shorts
  short* wfl = wfh + WFSZ;                  // 50176 shorts (offset 100352 B, 16-aligned)
  hipLaunchKernelGGL(wprep_kernel, dim3((WFSZ + 255) / 256), dim3(256), 0, stream,
                     W, wfh, wfl);
  hipLaunchKernelGGL(fused_kernel, dim3(BATCHES / NW), dim3(256), 0, stream,
                     X, wfh, wfl, out);
}